// Round 3
// baseline (322.717 us; speedup 1.0000x reference)
//
#include <hip/hip_runtime.h>

// OpeningP4: x [4,4,64,64,8] f32, kernel [3,3,3,8,16] f32 -> out [4,4,64,64,16] f32.
// Fully fused, zero-workspace (previous 2-kernel version assumed ws_size >= 33.5 MB,
// which is the prime suspect for the container faults).
//
// Math (derived from reference, verified vs numpy rot90 semantics):
//  ero[g,h,w,c,f]  = min_{k2,dy,dx} x[(g+k2-1)%4, h+dy-1, w+dx-1, c] - KE_g[dy,dx,k2,c,f]
//    KE_g[dy,dx,k2] = kero[r_g(2-dy,2-dx)][k2],
//    kero[i,j,0]=kernel[2-j,i,2], kero[i,j,1]=kernel[i,j,1], kero[i,j,2]=kernel[j,2-i,0]
//    r_0=(i,j) r_1=(j,2-i) r_2=(2-i,2-j) r_3=(2-j,i)   (numpy rot90 CCW)
//  out[b,j,h,w,f] = sum_c max_{k,dy,dx} ero[(j+k-1)%4, h+dy-1, w+dx-1, c, f]
//                                       + kernel[r_j(dy,dx)][k][c][f]
// OOB taps: skip (+inf pad for erosion, -inf for dilation). Center tap always valid.

#define HH 64
#define WW 64
#define CC 8
#define FF 16

#define NEG_INF (-__builtin_inff())
#define POS_INF (__builtin_inff())

__global__ __launch_bounds__(256) void opening_fused(
    const float* __restrict__ x,    // [4,4,64,64,8]
    const float* __restrict__ ker,  // [3,3,3,8,16]
    float* __restrict__ out)        // [4,4,64,64,16]
{
    // es4: eroded tile, layout [c][ey 0..9][ex 0..9][f4 0..3] of float4  (51200 B)
    // kbuf4: kernel staging, 864 float4                                  (13824 B)
    __shared__ float4 es4[CC * 10 * 10 * 4];
    __shared__ float4 kbuf4[3 * 3 * 3 * CC * 4];

    const int tid = threadIdx.x;
    const int tileX = blockIdx.x & 7;
    const int tileY = (blockIdx.x >> 3) & 7;
    const int j = (blockIdx.x >> 6) & 3;
    const int b = blockIdx.x >> 8;
    const int hy0 = tileY * 8 - 1;   // global h of es row 0
    const int wx0 = tileX * 8 - 1;

    // output mapping: each thread owns one (h,w) and 4 consecutive f
    const int q4 = tid & 3;          // f block: f = 4*q4 .. 4*q4+3
    const int owx = (tid >> 2) & 7;
    const int owy = tid >> 5;        // 0..7

    float4 acc[CC];
#pragma unroll
    for (int c = 0; c < CC; ++c)
        acc[c] = make_float4(NEG_INF, NEG_INF, NEG_INF, NEG_INF);

    const float4* ker4 = (const float4*)ker;

    for (int k = 0; k < 3; ++k) {
        const int gsrc = (j + k + 3) & 3;   // ero plane consumed by this k

        // ---- phase A: stage full erosion table KE_gsrc [dy][dx][k2][c][f4] ----
        for (int t = tid; t < 864; t += 256) {
            int q = t & 3;
            int c = (t >> 2) & 7;
            int rest = t >> 5;          // dy*9 + dx*3 + k2, [0,27)
            int k2 = rest % 3;
            int dxdy = rest / 3;
            int dx = dxdy % 3;
            int dy = dxdy / 3;
            int a0 = 2 - dy, b0 = 2 - dx;
            int i, jj;
            switch (gsrc) {
                case 0:  i = a0;      jj = b0;      break;
                case 1:  i = b0;      jj = 2 - a0;  break;
                case 2:  i = 2 - a0;  jj = 2 - b0;  break;
                default: i = 2 - b0;  jj = a0;      break;
            }
            int ka, kb, kc;
            if (k2 == 0)      { ka = 2 - jj; kb = i;      kc = 2; }
            else if (k2 == 1) { ka = i;      kb = jj;     kc = 1; }
            else              { ka = jj;     kb = 2 - i;  kc = 0; }
            kbuf4[t] = ker4[(((ka * 3 + kb) * 3 + kc) * CC + c) * 4 + q];
        }
        __syncthreads();

        // ---- phase B: compute eroded halo tile for plane gsrc into es4 ----
        for (int t = tid; t < 3200; t += 256) {
            int q = t & 3;
            int rest = t >> 2;          // c*100 + ey*10 + ex, [0,800)
            int ex = rest % 10;
            int tmp = rest / 10;
            int ey = tmp % 10;
            int c = tmp / 10;
            int h = hy0 + ey;
            int w = wx0 + ex;
            float4 best;
            if ((unsigned)h >= HH || (unsigned)w >= WW) {
                best = make_float4(NEG_INF, NEG_INF, NEG_INF, NEG_INF);
            } else {
                best = make_float4(POS_INF, POS_INF, POS_INF, POS_INF);
                const float* xb = x + (size_t)b * 4 * HH * WW * CC + c;
#pragma unroll
                for (int k2 = 0; k2 < 3; ++k2) {
                    int g2 = (gsrc + k2 + 3) & 3;
                    const float* xp = xb + (size_t)g2 * HH * WW * CC;
#pragma unroll
                    for (int dy = 0; dy < 3; ++dy) {
                        int hh = h + dy - 1;
                        if ((unsigned)hh >= HH) continue;
#pragma unroll
                        for (int dx = 0; dx < 3; ++dx) {
                            int ww2 = w + dx - 1;
                            if ((unsigned)ww2 >= WW) continue;
                            float xv = xp[(hh * WW + ww2) * CC];
                            float4 kv = kbuf4[((dy * 3 + dx) * 3 + k2) * 32 + c * 4 + q];
                            best.x = fminf(best.x, xv - kv.x);
                            best.y = fminf(best.y, xv - kv.y);
                            best.z = fminf(best.z, xv - kv.z);
                            best.w = fminf(best.w, xv - kv.w);
                        }
                    }
                }
            }
            es4[t] = best;   // t == (((c*10+ey)*10+ex)*4 + q)
        }
        __syncthreads();

        // ---- phase C: stage dilation slice kd[dy][dx][c][f4] = kernel[r_j(dy,dx)][k] ----
        for (int t = tid; t < 288; t += 256) {
            int q = t & 3;
            int c = (t >> 2) & 7;
            int dxdy = t >> 5;          // dy*3+dx, [0,9)
            int dx = dxdy % 3;
            int dy = dxdy / 3;
            int i, jj;
            switch (j) {
                case 0:  i = dy;      jj = dx;      break;
                case 1:  i = dx;      jj = 2 - dy;  break;
                case 2:  i = 2 - dy;  jj = 2 - dx;  break;
                default: i = 2 - dx;  jj = dy;      break;
            }
            kbuf4[t] = ker4[(((i * 3 + jj) * 3 + k) * CC + c) * 4 + q];
        }
        __syncthreads();

        // ---- phase D: accumulate running max (no bounds checks: OOB es == -inf) ----
#pragma unroll
        for (int c = 0; c < CC; ++c) {
            float4 a = acc[c];
#pragma unroll
            for (int dy = 0; dy < 3; ++dy) {
                int ey = owy + dy;
#pragma unroll
                for (int dx = 0; dx < 3; ++dx) {
                    int ex = owx + dx;
                    float4 e = es4[((c * 10 + ey) * 10 + ex) * 4 + q4];
                    float4 kv = kbuf4[((dy * 3 + dx) * CC + c) * 4 + q4];
                    a.x = fmaxf(a.x, e.x + kv.x);
                    a.y = fmaxf(a.y, e.y + kv.y);
                    a.z = fmaxf(a.z, e.z + kv.z);
                    a.w = fmaxf(a.w, e.w + kv.w);
                }
            }
            acc[c] = a;
        }
        __syncthreads();   // before next k overwrites kbuf4/es4
    }

    // ---- epilogue: sum over c, store float4 ----
    float4 s = acc[0];
#pragma unroll
    for (int c = 1; c < CC; ++c) {
        s.x += acc[c].x; s.y += acc[c].y; s.z += acc[c].z; s.w += acc[c].w;
    }
    const int h = tileY * 8 + owy;
    const int w = tileX * 8 + owx;
    float4* out4 = (float4*)out;
    out4[(((b * 4 + j) * HH + h) * WW + w) * 4 + q4] = s;
}

extern "C" void kernel_launch(void* const* d_in, const int* in_sizes, int n_in,
                              void* d_out, int out_size, void* d_ws, size_t ws_size,
                              hipStream_t stream) {
    const float* x = (const float*)d_in[0];     // [4,4,64,64,8]
    const float* ker = (const float*)d_in[1];   // [3,3,3,8,16]
    float* out = (float*)d_out;                 // [4,4,64,64,16]
    (void)d_ws; (void)ws_size;                  // deliberately unused

    // grid: b(4) x j(4) x 8x8 tiles = 1024 blocks
    opening_fused<<<1024, 256, 0, stream>>>(x, ker, out);
}

// Round 4
// 310.160 us; speedup vs baseline: 1.0405x; 1.0405x over previous
//
#include <hip/hip_runtime.h>

// OpeningP4: x [4,4,64,64,8] f32, kernel [3,3,3,8,16] f32 -> out [4,4,64,64,16] f32.
// Fused, zero-workspace. v3: LDS-staged x tile (+inf padded, c-major -> conflict-free,
// branch-free erosion taps), wave-uniform kv broadcasts, c-split es for 3 blocks/CU.
//
// Rotation algebra identical to the PASSED Round-2 kernel (absmax 0.0625).

#define HH 64
#define WW 64
#define CC 8
#define FF 16
#define NEG_INF (-__builtin_inff())
#define POS_INF (__builtin_inff())

__global__ __launch_bounds__(256, 3) void opening_fused(
    const float* __restrict__ x,    // [4,4,64,64,8]
    const float* __restrict__ ker,  // [3,3,3,8,16]
    float* __restrict__ out)        // [4,4,64,64,16]
{
    // 18432 + 25600 + 6912 + 2304 = 53248 B  -> 3 blocks/CU (3*53248 <= 163840)
    __shared__ float  xs[CC * 4 * 144];   // [c][g][r][s]: ((c*4+g)*144 + r*12 + s), +inf padded
    __shared__ float4 es4[4 * 4 * 100];   // [c4][q][pos]: ((c4*4+q)*100 + pos)
    __shared__ float4 ke4[27 * 4 * 4];    // [tap][c4][q]: tap = (dy*3+dx)*3+k2
    __shared__ float4 kd4[9 * 4 * 4];     // [dydx][c4][q]

    const int tid = threadIdx.x;
    const int tileX = blockIdx.x & 7;
    const int tileY = (blockIdx.x >> 3) & 7;
    const int j = (blockIdx.x >> 6) & 3;
    const int b = blockIdx.x >> 8;

    const float4* ker4 = (const float4*)ker;
    const float4* x4 = (const float4*)x;

    // ---- stage x tile: 4 planes, 12x12 halo, all 8 c; OOB = +inf (erosion-neutral) ----
    for (int t = tid; t < 1152; t += 256) {
        int q01 = t & 1;             // c half: c0 = 4*q01
        int cell = t >> 1;           // [0,576)
        int g = cell / 144;
        int rem = cell - g * 144;    // r*12+s
        int r = rem / 12;
        int s = rem - r * 12;
        int h = tileY * 8 - 2 + r;
        int w = tileX * 8 - 2 + s;
        float4 v;
        if ((unsigned)h < HH && (unsigned)w < WW)
            v = x4[(((b * 4 + g) * HH + h) * WW + w) * 2 + q01];
        else
            v = make_float4(POS_INF, POS_INF, POS_INF, POS_INF);
        int c0 = q01 * 4;
        xs[((c0 + 0) * 4 + g) * 144 + rem] = v.x;
        xs[((c0 + 1) * 4 + g) * 144 + rem] = v.y;
        xs[((c0 + 2) * 4 + g) * 144 + rem] = v.z;
        xs[((c0 + 3) * 4 + g) * 144 + rem] = v.w;
    }
    __syncthreads();

    // output ownership: q = tid&3 (f4 block), ox = (tid>>2)&7, oy = tid>>5
    const int q_o = tid & 3;
    const int ox = (tid >> 2) & 7;
    const int oy = tid >> 5;

    float4 acc[8];
#pragma unroll
    for (int c = 0; c < 8; ++c)
        acc[c] = make_float4(NEG_INF, NEG_INF, NEG_INF, NEG_INF);

    for (int k = 0; k < 3; ++k) {
        const int gsrc = (j + k + 3) & 3;   // ero plane consumed at SE depth k
#pragma unroll
        for (int cg = 0; cg < 2; ++cg) {
            // ---- stage KE (432 f4) + kd (144 f4) ----
            for (int t = tid; t < 576; t += 256) {
                if (t < 432) {
                    int q = t & 3;
                    int c4 = (t >> 2) & 3;
                    int tap = t >> 4;            // [0,27)
                    int k2 = tap % 3;
                    int dxdy = tap / 3;
                    int dx = dxdy % 3;
                    int dy = dxdy / 3;
                    int a0 = 2 - dy, b0 = 2 - dx;
                    int i, jj;
                    switch (gsrc) {
                        case 0:  i = a0;      jj = b0;      break;
                        case 1:  i = b0;      jj = 2 - a0;  break;
                        case 2:  i = 2 - a0;  jj = 2 - b0;  break;
                        default: i = 2 - b0;  jj = a0;      break;
                    }
                    int ka, kb, kc;
                    if (k2 == 0)      { ka = 2 - jj; kb = i;      kc = 2; }
                    else if (k2 == 1) { ka = i;      kb = jj;     kc = 1; }
                    else              { ka = jj;     kb = 2 - i;  kc = 0; }
                    int c = cg * 4 + c4;
                    ke4[t] = ker4[((ka * 3 + kb) * 3 + kc) * 32 + c * 4 + q];
                } else {
                    int u = t - 432;             // [0,144)
                    int q = u & 3;
                    int c4 = (u >> 2) & 3;
                    int dydx = u >> 4;           // [0,9)
                    int dx = dydx % 3;
                    int dy = dydx / 3;
                    int i, jj;
                    switch (j) {
                        case 0:  i = dy;      jj = dx;      break;
                        case 1:  i = dx;      jj = 2 - dy;  break;
                        case 2:  i = 2 - dy;  jj = 2 - dx;  break;
                        default: i = 2 - dx;  jj = dy;      break;
                    }
                    int c = cg * 4 + c4;
                    kd4[u] = ker4[((i * 3 + jj) * 3 + k) * 32 + c * 4 + q];
                }
            }
            __syncthreads();

            // ---- erosion: items id = c4*128 + p, p in [0,100) -> es4 ----
#pragma unroll
            for (int it = 0; it < 2; ++it) {
                int id = tid + it * 256;
                int c4 = id >> 7;               // wave-uniform
                int p = id & 127;
                if (p < 100) {
                    int ey = (p * 205) >> 11;   // p/10, exact for p<1024
                    int ex = p - ey * 10;
                    int h_es = tileY * 8 - 1 + ey;
                    int w_es = tileX * 8 - 1 + ex;
                    if ((unsigned)h_es < HH && (unsigned)w_es < WW) {
                        int c = cg * 4 + c4;
                        float xv[3][3][3];       // [k2][dy][dx]
#pragma unroll
                        for (int k2 = 0; k2 < 3; ++k2) {
                            int g2 = (gsrc + k2 + 3) & 3;
                            int base = (c * 4 + g2) * 144 + ey * 12 + ex;
#pragma unroll
                            for (int dy = 0; dy < 3; ++dy)
#pragma unroll
                                for (int dx = 0; dx < 3; ++dx)
                                    xv[k2][dy][dx] = xs[base + dy * 12 + dx];
                        }
#pragma unroll
                        for (int q = 0; q < 4; ++q) {
                            float4 best = make_float4(POS_INF, POS_INF, POS_INF, POS_INF);
#pragma unroll
                            for (int dy = 0; dy < 3; ++dy)
#pragma unroll
                                for (int dx = 0; dx < 3; ++dx)
#pragma unroll
                                    for (int k2 = 0; k2 < 3; ++k2) {
                                        float v = xv[k2][dy][dx];
                                        float4 kv = ke4[((dy * 3 + dx) * 3 + k2) * 16 + c4 * 4 + q];
                                        best.x = fminf(best.x, v - kv.x);
                                        best.y = fminf(best.y, v - kv.y);
                                        best.z = fminf(best.z, v - kv.z);
                                        best.w = fminf(best.w, v - kv.w);
                                    }
                            es4[(c4 * 4 + q) * 100 + p] = best;
                        }
                    } else {
                        float4 ninf = make_float4(NEG_INF, NEG_INF, NEG_INF, NEG_INF);
#pragma unroll
                        for (int q = 0; q < 4; ++q)
                            es4[(c4 * 4 + q) * 100 + p] = ninf;
                    }
                }
            }
            __syncthreads();

            // ---- dilation accumulate (4 c's of this group) ----
#pragma unroll
            for (int c4 = 0; c4 < 4; ++c4) {
                float4 a = acc[cg * 4 + c4];
#pragma unroll
                for (int dy = 0; dy < 3; ++dy)
#pragma unroll
                    for (int dx = 0; dx < 3; ++dx) {
                        int pos = (oy + dy) * 10 + (ox + dx);
                        float4 e = es4[(c4 * 4 + q_o) * 100 + pos];
                        float4 kv = kd4[(dy * 3 + dx) * 16 + c4 * 4 + q_o];
                        a.x = fmaxf(a.x, e.x + kv.x);
                        a.y = fmaxf(a.y, e.y + kv.y);
                        a.z = fmaxf(a.z, e.z + kv.z);
                        a.w = fmaxf(a.w, e.w + kv.w);
                    }
                acc[cg * 4 + c4] = a;
            }
            __syncthreads();   // before next phase overwrites ke4/kd4/es4
        }
    }

    // ---- epilogue: sum over c, coalesced float4 store ----
    float4 s = acc[0];
#pragma unroll
    for (int c = 1; c < 8; ++c) {
        s.x += acc[c].x; s.y += acc[c].y; s.z += acc[c].z; s.w += acc[c].w;
    }
    const int h = tileY * 8 + oy;
    const int w = tileX * 8 + ox;
    float4* out4 = (float4*)out;
    out4[(((b * 4 + j) * HH + h) * WW + w) * 4 + q_o] = s;
}

extern "C" void kernel_launch(void* const* d_in, const int* in_sizes, int n_in,
                              void* d_out, int out_size, void* d_ws, size_t ws_size,
                              hipStream_t stream) {
    const float* x = (const float*)d_in[0];
    const float* ker = (const float*)d_in[1];
    float* out = (float*)d_out;
    (void)d_ws; (void)ws_size;

    opening_fused<<<1024, 256, 0, stream>>>(x, ker, out);
}

// Round 5
// 293.328 us; speedup vs baseline: 1.1002x; 1.0574x over previous
//
#include <hip/hip_runtime.h>

// OpeningP4: x [4,4,64,64,8] f32, kernel [3,3,3,8,16] f32 -> out [4,4,64,64,16] f32.
// Fused, zero-workspace. v4: Round-4 structure with the register-spill eliminated:
// erosion is tap-outer / q-inner, scalar xs value consumed immediately (no xv[27]
// array -> no scratch). Rotation algebra identical to the PASSED kernels.

#define HH 64
#define WW 64
#define NEG_INF (-__builtin_inff())
#define POS_INF (__builtin_inff())

__global__ __launch_bounds__(256, 3) void opening_fused(
    const float* __restrict__ x,    // [4,4,64,64,8]
    const float* __restrict__ ker,  // [3,3,3,8,16]
    float* __restrict__ out)        // [4,4,64,64,16]
{
    // 18432 + 25600 + 6912 + 2304 = 53248 B -> 3 blocks/CU
    __shared__ float  xs[8 * 4 * 144];    // [c][g][r*12+s], +inf padded halo 12x12
    __shared__ float4 es4[4 * 4 * 100];   // [c4][q][pos]
    __shared__ float4 ke4[27 * 4 * 4];    // [tap][c4][q], tap=(dy*3+dx)*3+k2
    __shared__ float4 kd4[9 * 4 * 4];     // [dydx][c4][q]

    const int tid = threadIdx.x;
    const int tileX = blockIdx.x & 7;
    const int tileY = (blockIdx.x >> 3) & 7;
    const int j = (blockIdx.x >> 6) & 3;
    const int b = blockIdx.x >> 8;

    const float4* ker4 = (const float4*)ker;
    const float4* x4 = (const float4*)x;

    // ---- stage x tile: 4 planes, 12x12 halo, 8 c; OOB = +inf ----
    for (int t = tid; t < 1152; t += 256) {
        int q01 = t & 1;
        int cell = t >> 1;
        int g = cell / 144;
        int rem = cell - g * 144;
        int r = rem / 12;
        int s = rem - r * 12;
        int h = tileY * 8 - 2 + r;
        int w = tileX * 8 - 2 + s;
        float4 v;
        if ((unsigned)h < HH && (unsigned)w < WW)
            v = x4[(((b * 4 + g) * HH + h) * WW + w) * 2 + q01];
        else
            v = make_float4(POS_INF, POS_INF, POS_INF, POS_INF);
        int c0 = q01 * 4;
        xs[((c0 + 0) * 4 + g) * 144 + rem] = v.x;
        xs[((c0 + 1) * 4 + g) * 144 + rem] = v.y;
        xs[((c0 + 2) * 4 + g) * 144 + rem] = v.z;
        xs[((c0 + 3) * 4 + g) * 144 + rem] = v.w;
    }
    __syncthreads();

    const int q_o = tid & 3;
    const int ox = (tid >> 2) & 7;
    const int oy = tid >> 5;

    float4 acc[8];
#pragma unroll
    for (int c = 0; c < 8; ++c)
        acc[c] = make_float4(NEG_INF, NEG_INF, NEG_INF, NEG_INF);

    for (int k = 0; k < 3; ++k) {
        const int gsrc = (j + k + 3) & 3;
#pragma unroll
        for (int cg = 0; cg < 2; ++cg) {
            // ---- stage KE (432 f4) + kd (144 f4) for this (gsrc, cg, k) ----
            for (int t = tid; t < 576; t += 256) {
                if (t < 432) {
                    int q = t & 3;
                    int c4 = (t >> 2) & 3;
                    int tap = t >> 4;
                    int k2 = tap % 3;
                    int dxdy = tap / 3;
                    int dx = dxdy % 3;
                    int dy = dxdy / 3;
                    int a0 = 2 - dy, b0 = 2 - dx;
                    int i, jj;
                    switch (gsrc) {
                        case 0:  i = a0;      jj = b0;      break;
                        case 1:  i = b0;      jj = 2 - a0;  break;
                        case 2:  i = 2 - a0;  jj = 2 - b0;  break;
                        default: i = 2 - b0;  jj = a0;      break;
                    }
                    int ka, kb, kc;
                    if (k2 == 0)      { ka = 2 - jj; kb = i;      kc = 2; }
                    else if (k2 == 1) { ka = i;      kb = jj;     kc = 1; }
                    else              { ka = jj;     kb = 2 - i;  kc = 0; }
                    int c = cg * 4 + c4;
                    ke4[t] = ker4[((ka * 3 + kb) * 3 + kc) * 32 + c * 4 + q];
                } else {
                    int u = t - 432;
                    int q = u & 3;
                    int c4 = (u >> 2) & 3;
                    int dydx = u >> 4;
                    int dx = dydx % 3;
                    int dy = dydx / 3;
                    int i, jj;
                    switch (j) {
                        case 0:  i = dy;      jj = dx;      break;
                        case 1:  i = dx;      jj = 2 - dy;  break;
                        case 2:  i = 2 - dy;  jj = 2 - dx;  break;
                        default: i = 2 - dx;  jj = dy;      break;
                    }
                    int c = cg * 4 + c4;
                    kd4[u] = ker4[((i * 3 + jj) * 3 + k) * 32 + c * 4 + q];
                }
            }
            __syncthreads();

            // ---- erosion: items id = c4*128 + p; tap-outer, q-inner, no arrays ----
            for (int it = 0; it < 2; ++it) {
                int id = tid + (it << 8);
                int c4 = id >> 7;
                int p = id & 127;
                if (p >= 100) continue;
                int ey = (p * 205) >> 11;       // p/10
                int ex = p - ey * 10;
                int h_es = tileY * 8 - 1 + ey;
                int w_es = tileX * 8 - 1 + ex;
                float4 b0, b1, b2, b3;
                if ((unsigned)h_es < HH && (unsigned)w_es < WW) {
                    b0 = b1 = b2 = b3 = make_float4(POS_INF, POS_INF, POS_INF, POS_INF);
                    int c = cg * 4 + c4;
#pragma unroll
                    for (int k2 = 0; k2 < 3; ++k2) {
                        int g2 = (gsrc + k2 + 3) & 3;
                        int base = (c * 4 + g2) * 144 + ey * 12 + ex;
#pragma unroll
                        for (int dy = 0; dy < 3; ++dy)
#pragma unroll
                            for (int dx = 0; dx < 3; ++dx) {
                                float v = xs[base + dy * 12 + dx];
                                const float4* kk = &ke4[(((dy * 3 + dx) * 3 + k2) * 4 + c4) * 4];
                                float4 kv;
                                kv = kk[0];
                                b0.x = fminf(b0.x, v - kv.x); b0.y = fminf(b0.y, v - kv.y);
                                b0.z = fminf(b0.z, v - kv.z); b0.w = fminf(b0.w, v - kv.w);
                                kv = kk[1];
                                b1.x = fminf(b1.x, v - kv.x); b1.y = fminf(b1.y, v - kv.y);
                                b1.z = fminf(b1.z, v - kv.z); b1.w = fminf(b1.w, v - kv.w);
                                kv = kk[2];
                                b2.x = fminf(b2.x, v - kv.x); b2.y = fminf(b2.y, v - kv.y);
                                b2.z = fminf(b2.z, v - kv.z); b2.w = fminf(b2.w, v - kv.w);
                                kv = kk[3];
                                b3.x = fminf(b3.x, v - kv.x); b3.y = fminf(b3.y, v - kv.y);
                                b3.z = fminf(b3.z, v - kv.z); b3.w = fminf(b3.w, v - kv.w);
                            }
                    }
                } else {
                    b0 = b1 = b2 = b3 = make_float4(NEG_INF, NEG_INF, NEG_INF, NEG_INF);
                }
                int eb = (c4 * 4) * 100 + p;
                es4[eb] = b0; es4[eb + 100] = b1; es4[eb + 200] = b2; es4[eb + 300] = b3;
            }
            __syncthreads();

            // ---- dilation accumulate ----
#pragma unroll
            for (int c4 = 0; c4 < 4; ++c4) {
                float4 a = acc[cg * 4 + c4];
#pragma unroll
                for (int dy = 0; dy < 3; ++dy)
#pragma unroll
                    for (int dx = 0; dx < 3; ++dx) {
                        int pos = (oy + dy) * 10 + (ox + dx);
                        float4 e = es4[(c4 * 4 + q_o) * 100 + pos];
                        float4 kv = kd4[(dy * 3 + dx) * 16 + c4 * 4 + q_o];
                        a.x = fmaxf(a.x, e.x + kv.x);
                        a.y = fmaxf(a.y, e.y + kv.y);
                        a.z = fmaxf(a.z, e.z + kv.z);
                        a.w = fmaxf(a.w, e.w + kv.w);
                    }
                acc[cg * 4 + c4] = a;
            }
            __syncthreads();
        }
    }

    // ---- epilogue ----
    float4 s = acc[0];
#pragma unroll
    for (int c = 1; c < 8; ++c) {
        s.x += acc[c].x; s.y += acc[c].y; s.z += acc[c].z; s.w += acc[c].w;
    }
    const int h = tileY * 8 + oy;
    const int w = tileX * 8 + ox;
    float4* out4 = (float4*)out;
    out4[(((b * 4 + j) * HH + h) * WW + w) * 4 + q_o] = s;
}

extern "C" void kernel_launch(void* const* d_in, const int* in_sizes, int n_in,
                              void* d_out, int out_size, void* d_ws, size_t ws_size,
                              hipStream_t stream) {
    const float* x = (const float*)d_in[0];
    const float* ker = (const float*)d_in[1];
    float* out = (float*)d_out;
    (void)d_ws; (void)ws_size;

    opening_fused<<<1024, 256, 0, stream>>>(x, ker, out);
}